// Round 1
// baseline (288.656 us; speedup 1.0000x reference)
//
#include <hip/hip_runtime.h>

// K[i,j] = I0(2a*cos(pi*(x_i - y_j))) * exp(-2a),  a = 10
//
// Key observation: K depends only on u = |x_i - y_j| in [0,1), through a smooth
// 1-D function g(u) = i0e(z)*exp(|z|-2a), z = 2a*cos(pi*u). max|g''| ~ 18, so a
// piecewise-linear LUT with h = 1/2048 has abs interp error h^2*|g''|/8 ~ 5e-7,
// far below the harness-passing absmax of ~4.9e-4. This removes ALL per-element
// transcendentals (cos/rcp/exp/rsqrt, quarter-rate on CDNA) and both A&S
// polynomial branches: per element = sub, abs*scale, 2 cvt, sub, ds_read_b64, fma.
// The kernel becomes HBM-write-bound (268 MB output, floor ~41 us @ 6.5 TB/s).
//
// Table: 2049 float2 (base, delta) entries, 16.4 KB LDS, built once per block
// from the same A&S 9.8.1/9.8.2 polynomials (node values identical to the old
// per-element path). 1024 fat grid-stride blocks => table built 1024x (~1 us
// total), each block then streams ~16K float4 output chunks.

typedef float f32x4 __attribute__((ext_vector_type(4)));

#define TWO_A 20.0f
#define EXP_NEG_2A 2.0611536224385578e-9f   // exp(-20)
#define LOG2E 1.4426950408889634f
#define NTAB 2048
#define NBLOCKS 1024

__device__ __forceinline__ float bessel_g(float d) {
    // g(d) = i0e(z)*exp(|z|-2a), z = 2a*cos(pi*d). Works for any d (cos even).
#if __has_builtin(__builtin_amdgcn_cosf)
    float c = __builtin_amdgcn_cosf(0.5f * d);   // cos(pi*d), revolutions input
#else
    float c = __cosf(3.14159265358979323846f * d);
#endif
    float az = TWO_A * fabsf(c);             // |z| in [0, 20]

    // |z| < 3.75 : I0(z) = poly(t^2), t = z/3.75  (A&S 9.8.1)
    float t2 = az * (1.0f / 3.75f);
    t2 = t2 * t2;
    float ps = fmaf(t2, 0.0045813f, 0.0360768f);
    ps = fmaf(t2, ps, 0.2659732f);
    ps = fmaf(t2, ps, 1.2067492f);
    ps = fmaf(t2, ps, 3.0899424f);
    ps = fmaf(t2, ps, 3.5156229f);
    ps = fmaf(t2, ps, 1.0f);
    float k_small = ps * EXP_NEG_2A;

    // |z| >= 3.75 : sqrt(z)*i0e(z) = poly(3.75/z)  (A&S 9.8.2)
    float u = __fdividef(3.75f, az);
    float pl = fmaf(u, 0.00392377f, -0.01647633f);
    pl = fmaf(u, pl, 0.02635537f);
    pl = fmaf(u, pl, -0.02057706f);
    pl = fmaf(u, pl, 0.00916281f);
    pl = fmaf(u, pl, -0.00157565f);
    pl = fmaf(u, pl, 0.00225319f);
    pl = fmaf(u, pl, 0.01328592f);
    pl = fmaf(u, pl, 0.39894228f);
    float e = exp2f((az - TWO_A) * LOG2E);
    float k_large = pl * rsqrtf(az) * e;

    return (az < 3.75f) ? k_small : k_large;
}

__global__ __launch_bounds__(256) void bessel_lut_kernel(
    const float* __restrict__ x, const float* __restrict__ y,
    float* __restrict__ out, int log2cpr, size_t total)
{
    __shared__ float2 tab[NTAB + 1];

    // pass 1: node values g(k/NTAB) (k/2048 exact in fp32)
    for (int k = threadIdx.x; k <= NTAB; k += 256)
        tab[k].x = bessel_g((float)k * (1.0f / NTAB));
    __syncthreads();
    // pass 2: forward deltas (reads .x, writes .y — disjoint dwords, no race)
    for (int k = threadIdx.x; k <= NTAB; k += 256) {
        float gk = tab[k].x;
        float gk1 = (k < NTAB) ? tab[k + 1].x : gk;   // tab[NTAB].delta = 0
        tab[k].y = gk1 - gk;
    }
    __syncthreads();

    // grid-stride over float4 output chunks; chunk c -> row i = c>>log2cpr,
    // col j4 = (c & mask)*4, out offset = 4*c (row-major).
    const int jmask = (1 << log2cpr) - 1;
    const size_t stride = (size_t)gridDim.x * 256;
    for (size_t c = (size_t)blockIdx.x * 256 + threadIdx.x; c < total; c += stride) {
        const int i = (int)(c >> log2cpr);
        const int j4 = ((int)c & jmask) << 2;
        const float xi = x[i];                               // L1-hot broadcast
        const f32x4 yv = *reinterpret_cast<const f32x4*>(y + j4);  // L1-hot

        f32x4 o;
#pragma unroll
        for (int e = 0; e < 4; ++e) {
            float t = fminf(fabsf(xi - yv[e]) * (float)NTAB, (float)NTAB);
            int k = (int)t;                  // t >= 0, trunc == floor
            float f = t - (float)k;
            float2 te = tab[k];              // ds_read_b64
            o[e] = fmaf(f, te.y, te.x);
        }
        __builtin_nontemporal_store(o, reinterpret_cast<f32x4*>(out) + c);
    }
}

// Fallback for shapes where ny/4 isn't a power of two: old analytic 2D kernel.
__global__ __launch_bounds__(256) void bessel_fallback_kernel(
    const float* __restrict__ x, const float* __restrict__ y,
    float* __restrict__ out, int nx, int ny)
{
    const int i = blockIdx.y;
    const int j4 = (blockIdx.x * 256 + threadIdx.x) * 4;
    if (i >= nx || j4 >= ny) return;

    const float xi = x[i];
    float* orow = out + (size_t)i * (size_t)ny;

    if (j4 + 3 < ny) {
        float4 yv = *reinterpret_cast<const float4*>(y + j4);
        float4 o;
        o.x = bessel_g(xi - yv.x);
        o.y = bessel_g(xi - yv.y);
        o.z = bessel_g(xi - yv.z);
        o.w = bessel_g(xi - yv.w);
        *reinterpret_cast<float4*>(orow + j4) = o;
    } else {
        for (int j = j4; j < ny; ++j)
            orow[j] = bessel_g(xi - y[j]);
    }
}

extern "C" void kernel_launch(void* const* d_in, const int* in_sizes, int n_in,
                              void* d_out, int out_size, void* d_ws, size_t ws_size,
                              hipStream_t stream) {
    const float* x = (const float*)d_in[0];
    const float* y = (const float*)d_in[1];
    float* out = (float*)d_out;
    const int nx = in_sizes[0];
    const int ny = in_sizes[1];

    const int cpr = ny >> 2;  // float4 chunks per row
    const bool fast = (ny >= 4) && ((ny & 3) == 0) && ((cpr & (cpr - 1)) == 0);

    if (fast) {
        const int log2cpr = __builtin_ctz(cpr);
        const size_t total = (size_t)nx << log2cpr;
        int blocks = (int)((total + 255) / 256);
        if (blocks > NBLOCKS) blocks = NBLOCKS;
        bessel_lut_kernel<<<blocks, 256, 0, stream>>>(x, y, out, log2cpr, total);
    } else {
        const int jblocks = (ny + 4 * 256 - 1) / (4 * 256);
        dim3 grid(jblocks, nx);
        bessel_fallback_kernel<<<grid, 256, 0, stream>>>(x, y, out, nx, ny);
    }
}

// Round 2
// 270.492 us; speedup vs baseline: 1.0672x; 1.0672x over previous
//
#include <hip/hip_runtime.h>

// K[i,j] = I0(2a*cos(pi*(x_i - y_j))) * exp(-2a),  a = 10
//
// g(u) = i0e(z)*exp(|z|-2a), z = 2a*cos(pi*u), u = |x_i - y_j| in [0,1].
// Piecewise-linear LUT over u with h = 1/512: abs interp err h^2*|g''|max/8
// ~ 8.5e-6 (|g''|max ~ 17.7), far below the observed 4.88e-4 reference floor.
//
// Round-1 post-mortem: random-index ds_read_b64 gather into a single-copy
// table is ~8-way bank-conflicted => ~0.375 serialized LDS cyc/elem per CU,
// EQUAL to the 0.377 cyc/elem HBM write budget -> kernel was gather-bound.
// This version:
//   * 16 bank-interleaved table copies (entry k, copy c at dword k*16+c;
//     lane reads copy lane&15) -> ~2 accesses/bank/wave ~= conflict-free.
//   * two ds_read_b32 (g[k] & g[k+1] via offset:64) replace the b64.
//   * block owns 8 rows; y float4s preloaded to registers once per block
//     (statically indexed, fully unrolled); x[i] is a block-uniform scalar.
//   * nontemporal float4 stores; kernel should be purely write-bound (~43 us).

typedef float f32x4 __attribute__((ext_vector_type(4)));

#define TWO_A 20.0f
#define EXP_NEG_2A 2.0611536224385578e-9f   // exp(-20)
#define LOG2E 1.4426950408889634f

#define NTAB 512                 // intervals over u in [0,1]
#define NCOPY 16                 // bank-interleaved copies
#define TAB_ENTRIES (NTAB + 2)   // k can reach NTAB by fp rounding; +1 for k+1
#define ROWS_PER_BLOCK 8
#define CPT 8                    // float4 chunks per thread per row (ny=8192)

__device__ __forceinline__ float bessel_g(float d) {
    // g(d) = i0e(z)*exp(|z|-2a), z = 2a*cos(pi*d) (even in d).
#if __has_builtin(__builtin_amdgcn_cosf)
    float c = __builtin_amdgcn_cosf(0.5f * d);   // cos(pi*d), revolutions input
#else
    float c = __cosf(3.14159265358979323846f * d);
#endif
    float az = TWO_A * fabsf(c);             // |z| in [0, 20]

    // |z| < 3.75 : I0(z) = poly(t^2), t = z/3.75  (A&S 9.8.1)
    float t2 = az * (1.0f / 3.75f);
    t2 = t2 * t2;
    float ps = fmaf(t2, 0.0045813f, 0.0360768f);
    ps = fmaf(t2, ps, 0.2659732f);
    ps = fmaf(t2, ps, 1.2067492f);
    ps = fmaf(t2, ps, 3.0899424f);
    ps = fmaf(t2, ps, 3.5156229f);
    ps = fmaf(t2, ps, 1.0f);
    float k_small = ps * EXP_NEG_2A;

    // |z| >= 3.75 : sqrt(z)*i0e(z) = poly(3.75/z)  (A&S 9.8.2)
    float u = __fdividef(3.75f, az);
    float pl = fmaf(u, 0.00392377f, -0.01647633f);
    pl = fmaf(u, pl, 0.02635537f);
    pl = fmaf(u, pl, -0.02057706f);
    pl = fmaf(u, pl, 0.00916281f);
    pl = fmaf(u, pl, -0.00157565f);
    pl = fmaf(u, pl, 0.00225319f);
    pl = fmaf(u, pl, 0.01328592f);
    pl = fmaf(u, pl, 0.39894228f);
    float e = exp2f((az - TWO_A) * LOG2E);
    float k_large = pl * rsqrtf(az) * e;

    return (az < 3.75f) ? k_small : k_large;
}

__global__ __launch_bounds__(256, 4) void bessel_lut_kernel(
    const float* __restrict__ x, const float* __restrict__ y,
    float* __restrict__ out, int nx)     // fast path: ny == 8192 fixed
{
    __shared__ float nodes[TAB_ENTRIES];
    __shared__ float tab[TAB_ENTRIES * NCOPY];

    const int tid = threadIdx.x;

    // pass 1: node values g(k/NTAB) (k/512 exact in fp32); entries NTAB..NTAB+1
    // clamp to u=1 (only reachable via |d|~1 rounding up, g continuous there).
    for (int k = tid; k < TAB_ENTRIES; k += 256)
        nodes[k] = bessel_g(fminf((float)k * (1.0f / NTAB), 1.0f));
    __syncthreads();
    // pass 2: replicate, bank-interleaved: entry k copy c -> dword k*NCOPY+c.
    // Writes: consecutive lanes -> consecutive dwords (conflict-free);
    // reads: 16-lane broadcast per node.
    for (int w = tid; w < TAB_ENTRIES * NCOPY; w += 256)
        tab[w] = nodes[w >> 4];
    __syncthreads();

    // preload this thread's 8 y-float4s into registers (reused for all rows)
    f32x4 yv[CPT];
#pragma unroll
    for (int it = 0; it < CPT; ++it)
        yv[it] = *reinterpret_cast<const f32x4*>(y + (((it << 8) + tid) << 2));

    const float* tb = &tab[tid & (NCOPY - 1)];   // per-lane copy base

    const int row0 = blockIdx.x * ROWS_PER_BLOCK;
    for (int rr = 0; rr < ROWS_PER_BLOCK; ++rr) {
        const int i = row0 + rr;
        if (i >= nx) return;
        const float xi = x[i];                   // block-uniform -> scalar load
        f32x4* orow = reinterpret_cast<f32x4*>(out + ((size_t)i << 13));
#pragma unroll
        for (int it = 0; it < CPT; ++it) {       // static yv indexing (rule #20)
            f32x4 o;
#pragma unroll
            for (int e = 0; e < 4; ++e) {
                float t = fabsf(xi - yv[it][e]) * (float)NTAB;  // [0, 512]
                int k = (int)t;                  // t >= 0: trunc == floor
                float f = t - (float)k;
                float g0 = tb[k << 4];           // ds_read_b32
                float g1 = tb[(k << 4) + 16];    // ds_read_b32 offset:64
                o[e] = fmaf(f, g1 - g0, g0);
            }
            __builtin_nontemporal_store(o, orow + (it << 8) + tid);
        }
    }
}

// Fallback for any other shape: analytic 2D kernel (round-0 version).
__global__ __launch_bounds__(256) void bessel_fallback_kernel(
    const float* __restrict__ x, const float* __restrict__ y,
    float* __restrict__ out, int nx, int ny)
{
    const int i = blockIdx.y;
    const int j4 = (blockIdx.x * 256 + threadIdx.x) * 4;
    if (i >= nx || j4 >= ny) return;

    const float xi = x[i];
    float* orow = out + (size_t)i * (size_t)ny;

    if (j4 + 3 < ny) {
        float4 yy = *reinterpret_cast<const float4*>(y + j4);
        float4 o;
        o.x = bessel_g(xi - yy.x);
        o.y = bessel_g(xi - yy.y);
        o.z = bessel_g(xi - yy.z);
        o.w = bessel_g(xi - yy.w);
        *reinterpret_cast<float4*>(orow + j4) = o;
    } else {
        for (int j = j4; j < ny; ++j)
            orow[j] = bessel_g(xi - y[j]);
    }
}

extern "C" void kernel_launch(void* const* d_in, const int* in_sizes, int n_in,
                              void* d_out, int out_size, void* d_ws, size_t ws_size,
                              hipStream_t stream) {
    const float* x = (const float*)d_in[0];
    const float* y = (const float*)d_in[1];
    float* out = (float*)d_out;
    const int nx = in_sizes[0];
    const int ny = in_sizes[1];

    if (ny == 8192) {
        const int blocks = (nx + ROWS_PER_BLOCK - 1) / ROWS_PER_BLOCK;
        bessel_lut_kernel<<<blocks, 256, 0, stream>>>(x, y, out, nx);
    } else {
        const int jblocks = (ny + 4 * 256 - 1) / (4 * 256);
        dim3 grid(jblocks, ny ? nx : 0);
        bessel_fallback_kernel<<<grid, 256, 0, stream>>>(x, y, out, nx, ny);
    }
}